// Round 6
// baseline (97.601 us; speedup 1.0000x reference)
//
#include <hip/hip_runtime.h>
#include <hip/hip_bf16.h>
#include <math.h>

namespace {
constexpr int NB = 512;   // batches
constexpr int NK = 1024;  // tokens per batch
constexpr int NM = 64;    // interests per batch
constexpr int ND = 128;   // feature dim
constexpr float ALPHA_T_TO_I = 0.3f;
}

typedef __attribute__((ext_vector_type(8))) short short8;   // 8 bf16 — MFMA A/B frag
typedef __attribute__((ext_vector_type(4))) short short4v;  // 8 B LDS store
typedef __attribute__((ext_vector_type(4))) float f32x4;    // MFMA C/D frag
typedef __attribute__((ext_vector_type(2))) unsigned uint2v;
typedef __attribute__((ext_vector_type(4))) unsigned uint4v;

// Pack 2 floats -> 2 bf16 (RNE) as one u32; compiler emits v_cvt_pk_bf16_f32.
__device__ __forceinline__ unsigned pk2_bf16(float a, float b) {
  const __hip_bfloat162_raw r =
      static_cast<__hip_bfloat162_raw>(__float22bfloat162_rn(make_float2(a, b)));
  return (unsigned)r.x | ((unsigned)r.y << 16);  // identity recombine, folds away
}

__device__ __forceinline__ short4v pk4_bf16(float a, float b, float c, float d) {
  uint2v p;
  p.x = pk2_bf16(a, b);
  p.y = pk2_bf16(c, d);
  return __builtin_bit_cast(short4v, p);
}

// One block per batch (512 blocks = exactly 2/CU), 4 waves. Wave w owns token
// rows [w*256, w*256+256). Interests: normalized bf16 in LDS once, 16 B-frags
// hoisted to VGPRs. Tokens: streamed from HBM in fragment order into a single
// 32-VGPR buffer with depth-1 rotation prefetch. Finalize fused via
// fence+counter last-block-done reduction (no second kernel launch).
__global__ __launch_bounds__(256, 2) void chamfer_mfma(
    const float* __restrict__ tokens,
    const float* __restrict__ interests,
    float* __restrict__ partial,   // [b] = sum_m mindist ; [NB+b] = sum_k mindist
    int* __restrict__ ctr,         // zeroed by hipMemsetAsync each call
    float* __restrict__ out)
{
  const int b    = blockIdx.x;
  const int tid  = threadIdx.x;
  const int lane = tid & 63;
  const int wave = tid >> 6;

  __shared__ __align__(16) short iLds[NM * ND];  // normalized interests bf16 (16 KB)
  __shared__ float colW[4][4][16];
  __shared__ float rowW[4];
  __shared__ int isLast;

  const float* __restrict__ ib = interests + (size_t)b * NM * ND;
  const float* __restrict__ tb = tokens    + (size_t)b * NK * ND;

  const int colOff  = (lane >> 4) * 8;
  const int rowBase = wave * (NK / 4) + (lane & 15);

  // Prologue: issue tile 0's loads before phase 0 (independent of LDS work).
  float4 v[8];
  {
    const float* tp = tb + (size_t)rowBase * ND + colOff;
#pragma unroll
    for (int q = 0; q < 4; ++q) {
      v[2 * q]     = *reinterpret_cast<const float4*>(tp + q * 32);
      v[2 * q + 1] = *reinterpret_cast<const float4*>(tp + q * 32 + 4);
    }
  }

  // ---- Phase 0: interests -> row-normalize -> bf16 LDS ----
  for (int it = 0; it < (NM * ND / 4) / 256; ++it) {   // 8 iters
    const int idx = it * 256 + tid;                    // float4 index; row = idx>>5
    const float4 w = reinterpret_cast<const float4*>(ib)[idx];
    float s = fmaf(w.x, w.x, fmaf(w.y, w.y, fmaf(w.z, w.z, w.w * w.w)));
    s += __shfl_xor(s, 1);  s += __shfl_xor(s, 2);  s += __shfl_xor(s, 4);
    s += __shfl_xor(s, 8);  s += __shfl_xor(s, 16);
    const float rn = 1.0f / fmaxf(sqrtf(s), 1e-12f);
    reinterpret_cast<short4v*>(iLds)[idx] =
        pk4_bf16(w.x * rn, w.y * rn, w.z * rn, w.w * rn);
  }
  __syncthreads();

  // ---- Hoist all 16 B-fragments into VGPRs ----
  // Lane holds I_hat[c*16 + (lane&15)][q*32 + (lane>>4)*8 + i].
  short8 bfr[4][4];
#pragma unroll
  for (int c = 0; c < 4; ++c)
#pragma unroll
    for (int q = 0; q < 4; ++q) {
      const int off = (c * 16 + (lane & 15)) * ND + q * 32 + ((lane >> 4) * 8);
      bfr[c][q] = *reinterpret_cast<const short8*>(&iLds[off]);
    }

  float colMax[4] = {-2.f, -2.f, -2.f, -2.f};
  float rowSum = 0.f;

#pragma unroll 1
  for (int rt = 0; rt < 16; ++rt) {
    // Consume v: row norm + bf16 A-fragments (v dead after this block).
    float ssq = 0.f;
#pragma unroll
    for (int j = 0; j < 8; ++j) {
      ssq = fmaf(v[j].x, v[j].x, ssq); ssq = fmaf(v[j].y, v[j].y, ssq);
      ssq = fmaf(v[j].z, v[j].z, ssq); ssq = fmaf(v[j].w, v[j].w, ssq);
    }
    ssq += __shfl_xor(ssq, 16);
    ssq += __shfl_xor(ssq, 32);
    const float rn = 1.0f / fmaxf(sqrtf(ssq), 1e-12f);

    short8 af[4];
#pragma unroll
    for (int q = 0; q < 4; ++q) {
      uint4v p;
      p.x = pk2_bf16(v[2 * q].x * rn,     v[2 * q].y * rn);
      p.y = pk2_bf16(v[2 * q].z * rn,     v[2 * q].w * rn);
      p.z = pk2_bf16(v[2 * q + 1].x * rn, v[2 * q + 1].y * rn);
      p.w = pk2_bf16(v[2 * q + 1].z * rn, v[2 * q + 1].w * rn);
      af[q] = __builtin_bit_cast(short8, p);
    }

    // Depth-1 prefetch: next tile's loads into the same registers, issued
    // BEFORE the MFMA/reduction block so they fly during compute.
    if (rt + 1 < 16) {
      const float* tp = tb + (size_t)(rowBase + (rt + 1) * 16) * ND + colOff;
#pragma unroll
      for (int q = 0; q < 4; ++q) {
        v[2 * q]     = *reinterpret_cast<const float4*>(tp + q * 32);
        v[2 * q + 1] = *reinterpret_cast<const float4*>(tp + q * 32 + 4);
      }
    }

    f32x4 acc[4];
#pragma unroll
    for (int c = 0; c < 4; ++c) acc[c] = (f32x4){0.f, 0.f, 0.f, 0.f};
#pragma unroll
    for (int c = 0; c < 4; ++c)
#pragma unroll
      for (int q = 0; q < 4; ++q)
        acc[c] = __builtin_amdgcn_mfma_f32_16x16x32_bf16(af[q], bfr[c][q], acc[c], 0, 0, 0);

    // Row-max (token -> nearest interest): C row = (lane>>4)*4+i, col = lane&15 (+16c).
#pragma unroll
    for (int i = 0; i < 4; ++i) {
      float rm = fmaxf(fmaxf(acc[0][i], acc[1][i]), fmaxf(acc[2][i], acc[3][i]));
      rm = fmaxf(rm, __shfl_xor(rm, 1));
      rm = fmaxf(rm, __shfl_xor(rm, 2));
      rm = fmaxf(rm, __shfl_xor(rm, 4));
      rm = fmaxf(rm, __shfl_xor(rm, 8));
      if ((lane & 15) == 0)
        rowSum += sqrtf(fmaxf(2.0f - 2.0f * rm, 1e-12f));
    }
    // Col-max (interest -> nearest token) over this lane's 4 token rows.
#pragma unroll
    for (int c = 0; c < 4; ++c) {
      const float m01 = fmaxf(acc[c][0], acc[c][1]);
      const float m23 = fmaxf(acc[c][2], acc[c][3]);
      colMax[c] = fmaxf(colMax[c], fmaxf(m01, m23));
    }
  }

  // Combine col-max across the wave's 4 row-groups.
#pragma unroll
  for (int c = 0; c < 4; ++c) {
    colMax[c] = fmaxf(colMax[c], __shfl_xor(colMax[c], 16));
    colMax[c] = fmaxf(colMax[c], __shfl_xor(colMax[c], 32));
  }
  if (lane < 16)
#pragma unroll
    for (int c = 0; c < 4; ++c) colW[wave][c][lane] = colMax[c];

  // Wave-total token dist sum (nonzero only on lanes 0,16,32,48).
  rowSum += __shfl_xor(rowSum, 1);  rowSum += __shfl_xor(rowSum, 2);
  rowSum += __shfl_xor(rowSum, 4);  rowSum += __shfl_xor(rowSum, 8);
  rowSum += __shfl_xor(rowSum, 16); rowSum += __shfl_xor(rowSum, 32);
  if (lane == 0) rowW[wave] = rowSum;
  __syncthreads();

  if (tid < NM) {  // m == tid: c = tid>>4, j = tid&15 -> m = c*16+j = tid
    const int c = tid >> 4, j = tid & 15;
    const float v2 = fmaxf(fmaxf(colW[0][c][j], colW[1][c][j]),
                           fmaxf(colW[2][c][j], colW[3][c][j]));
    float dist = sqrtf(fmaxf(2.0f - 2.0f * v2, 1e-12f));
    dist += __shfl_xor(dist, 1);  dist += __shfl_xor(dist, 2);
    dist += __shfl_xor(dist, 4);  dist += __shfl_xor(dist, 8);
    dist += __shfl_xor(dist, 16); dist += __shfl_xor(dist, 32);
    if (tid == 0) {
      // Device-scope coherent stores of this block's partials.
      atomicExch(&partial[b],      dist);
      atomicExch(&partial[NB + b], rowW[0] + rowW[1] + rowW[2] + rowW[3]);
    }
  }

  // ---- Fused finalize: last block to arrive reduces all partials ----
  __threadfence();
  __syncthreads();
  if (tid == 0)
    isLast = (atomicAdd(ctr, 1) == (int)gridDim.x - 1);
  __syncthreads();
  if (isLast) {
    __threadfence();  // acquire: make all blocks' partial[] visible
    float* red = reinterpret_cast<float*>(iLds);  // reuse LDS as f32 scratch
    const int t = tid;
    red[t]       = partial[t] + partial[t + 256];
    red[256 + t] = partial[NB + t] + partial[NB + t + 256];
    __syncthreads();
    for (int off = 128; off; off >>= 1) {
      if (t < off) { red[t] += red[t + off]; red[256 + t] += red[256 + t + off]; }
      __syncthreads();
    }
    if (t == 0) {
      const float loss_i_to_t = red[0]   * (1.0f / (float)(NB * NM));
      const float loss_t_to_i = red[256] * (1.0f / (float)(NB * NK));
      out[0] = loss_i_to_t + ALPHA_T_TO_I * loss_t_to_i;
    }
  }
}

extern "C" void kernel_launch(void* const* d_in, const int* in_sizes, int n_in,
                              void* d_out, int out_size, void* d_ws, size_t ws_size,
                              hipStream_t stream) {
  const float* tokens    = (const float*)d_in[0];  // (512, 1024, 128) f32
  const float* interests = (const float*)d_in[1];  // (512, 64, 128) f32
  int*   ctr     = (int*)d_ws;                          // 1 int, zeroed each call
  float* partial = (float*)((char*)d_ws + 256);         // 2*NB floats
  float* out     = (float*)d_out;

  (void)hipMemsetAsync(ctr, 0, sizeof(int), stream);  // capture-safe async memset
  chamfer_mfma<<<dim3(NB), dim3(256), 0, stream>>>(tokens, interests, partial, ctr, out);
}